// Round 1
// baseline (423.329 us; speedup 1.0000x reference)
//
#include <hip/hip_runtime.h>
#include <math.h>

// ============================================================================
// GetImportantStruct — round 3: same 11-dispatch fused pipeline, bulk row
// copies upgraded to float4 (16B/lane): pass4 does 2 inform rows per wave
// (32 lanes x float4 = one 512B row per half-wave), pass5 does 2 br_feature
// rows per block (128 lanes x float4 = one 2KB row). All else unchanged from
// the harness-verified 434us version.
// ============================================================================

// ---------------- fused counting: batch (N) and br_batch (N2) ---------------
__global__ void k_count_both(const int* __restrict__ batch, int N,
                             const int* __restrict__ br_batch, int N2,
                             int* __restrict__ counts, int* __restrict__ counts2){
  int i = blockIdx.x*blockDim.x + threadIdx.x;
  if (i < N) atomicAdd(&counts[batch[i]], 1);
  else if (i < N + N2) atomicAdd(&counts2[br_batch[i - N]], 1);
}

// ---------------- G-length exclusive scans (single block, 512 threads) ------
__device__ void scan512_excl(const int* __restrict__ in, int* __restrict__ out,
                             int G, int* s){
  int t = threadIdx.x;
  int v = (t < G) ? in[t] : 0;
  s[t] = v; __syncthreads();
  for (int off = 1; off < 512; off <<= 1){
    int add = (t >= off) ? s[t - off] : 0;
    __syncthreads();
    s[t] += add;
    __syncthreads();
  }
  if (t < G) out[t] = s[t] - v;
  __syncthreads();
}

__global__ void k_scanG(const int* __restrict__ counts, const int* __restrict__ counts2,
                        const int* __restrict__ edge_num, int G,
                        int* __restrict__ node_off, int* __restrict__ node_off2,
                        int* __restrict__ e_off){
  __shared__ int s[512];
  scan512_excl(counts,  node_off,  G, s);
  scan512_excl(counts2, node_off2, G, s);
  scan512_excl(edge_num, e_off,    G, s);
}

// ---------------- score / x_out / low / rem-init: one WAVE per node ---------
// Row (C floats) held in registers (C<=2048 -> <=8 float4/lane), butterfly
// shfl reduction, single global pass. sigmoid(m)<0.5  <=>  dot<0.
__global__ void __launch_bounds__(256) k_score(
    const float* __restrict__ x, const float* __restrict__ W,
    const int* __restrict__ batch, const int* __restrict__ counts,
    const int* __restrict__ node_off,
    float* __restrict__ out_x, int* __restrict__ low, int* __restrict__ rem,
    int C, int N){
  int wave = (blockIdx.x * blockDim.x + threadIdx.x) >> 6;
  int lane = threadIdx.x & 63;
  if (wave >= N) return;
  const float4* x4 = (const float4*)(x + (size_t)wave * C);
  const float4* W4 = (const float4*)W;
  const int nv = C >> 2;
  float4 vals[8];
  float acc = 0.f;
  int m = 0;
  for (int k = lane; k < nv; k += 64){
    float4 a = x4[k]; float4 w = W4[k];
    acc += a.x*w.x + a.y*w.y + a.z*w.z + a.w*w.w;
    if (m < 8) vals[m] = a;
    m++;
  }
  #pragma unroll
  for (int d = 1; d < 64; d <<= 1) acc += __shfl_xor(acc, d, 64);
  // all lanes now hold the full dot product
  float scale = 2.0f / (1.0f + expf(-acc / (float)C));   // 2*sigmoid(mean)
  if (lane == 0){
    int g    = batch[wave];
    int last = node_off[g] + counts[g] - 1;
    low[wave] = (acc < 0.0f) && (wave != last) ? 1 : 0;
    rem[wave] = -1;
  }
  float4* o4 = (float4*)(out_x + (size_t)wave * C);
  m = 0;
  for (int k = lane; k < nv; k += 64){
    float4 a = (m < 8) ? vals[m] : x4[k];
    m++;
    a.x *= scale; a.y *= scale; a.z *= scale; a.w *= scale;
    o4[k] = a;
  }
}

// ---------------- edge -> graph lookup --------------------------------------
__device__ __forceinline__ int find_graph(const int* __restrict__ e_off, int G, int e){
  int lo = 0, hi = G - 1;            // largest g with e_off[g] <= e
  while (lo < hi){
    int mid = (lo + hi + 1) >> 1;
    if (e_off[mid] <= e) lo = mid; else hi = mid - 1;
  }
  return lo;
}

// ---------------- pass1: candidate edges (E) + br drop scatter (N) ----------
__global__ void k_pass1(const int* __restrict__ ei, const int* __restrict__ e_off,
                        const int* __restrict__ node_off, const int* __restrict__ node_off2,
                        const int* __restrict__ counts, const int* __restrict__ batch,
                        const int* __restrict__ low, const int* __restrict__ br_com_num,
                        int* __restrict__ rem, int* __restrict__ brmask,
                        int E, int N, int G){
  int e = blockIdx.x*blockDim.x + threadIdx.x;
  if (e < N && low[e]){                       // br-drop scatter for node e
    int g = batch[e];
    int d = e - node_off[g] + br_com_num[g] + node_off2[g];
    brmask[d] = 1;                            // 1 = dropped (mask pre-zeroed)
  }
  if (e >= E) return;
  int g  = find_graph(e_off, G, e);
  if (e - e_off[g] < 1) return;               // local_pos >= 1
  int dst  = ei[E + e];
  int last = node_off[g] + counts[g] - 1;
  if (dst != last) return;
  int src = ei[e];
  if (!low[src]) return;
  if (batch[src] != g) return;
  atomicMax(&rem[src], e);
}

// ---------------- pass2: edge keep blocksums + dropcnt (E) | brmask sums (N2)
__global__ void k_pass2(const int* __restrict__ ei, const int* __restrict__ rem,
                        const int* __restrict__ e_off, const int* __restrict__ brmask,
                        int* __restrict__ dropcnt,
                        int* __restrict__ bsumsA, int* __restrict__ bsumsB,
                        int E, int N2, int G, int nbE){
  __shared__ int s[256];
  int b = blockIdx.x, t = threadIdx.x;
  int v = 0;
  if (b < nbE){
    int e = b*256 + t;
    if (e < E){
      v = (rem[ei[e]] != e) ? 1 : 0;
      if (!v){ int g = find_graph(e_off, G, e); atomicAdd(&dropcnt[g], 1); }
    }
  } else {
    int j = (b - nbE)*256 + t;
    v = (j < N2) ? (brmask[j] == 0) : 0;
  }
  s[t] = v; __syncthreads();
  for (int off = 128; off > 0; off >>= 1){
    if (t < off) s[t] += s[t + off];
    __syncthreads();
  }
  if (t == 0){
    if (b < nbE) bsumsA[b] = s[0];
    else         bsumsB[b - nbE] = s[0];
  }
}

// ---------------- scan helpers ----------------------------------------------
__device__ void scan_bsums_dev(int* __restrict__ bsums, int nb, int* __restrict__ total){
  __shared__ int s[1024];
  int t = threadIdx.x;
  int v = (t < nb) ? bsums[t] : 0;
  s[t] = v; __syncthreads();
  for (int off = 1; off < 1024; off <<= 1){
    int add = (t >= off) ? s[t - off] : 0;
    __syncthreads();
    s[t] += add;
    __syncthreads();
  }
  if (t < nb)      bsums[t] = s[t] - v;
  if (t == nb - 1) *total   = s[t];
}

__global__ void k_scanAB(int* __restrict__ bsumsA, int nbA,
                         int* __restrict__ bsumsB, int nbB,
                         int* __restrict__ totals){
  if (blockIdx.x == 0) scan_bsums_dev(bsumsA, nbA, &totals[0]);
  else                 scan_bsums_dev(bsumsB, nbB, &totals[1]);
}

__global__ void k_scanC(int* __restrict__ bsumsC, int nb, int* __restrict__ totals){
  scan_bsums_dev(bsumsC, nb, &totals[2]);
}

__device__ __forceinline__ int excl_scan256(int v, int* s){
  int t = threadIdx.x;
  s[t] = v; __syncthreads();
  for (int off = 1; off < 256; off <<= 1){
    int add = (t >= off) ? s[t - off] : 0;
    __syncthreads();
    s[t] += add;
    __syncthreads();
  }
  return s[t] - v;
}

// ---------------- pass3: edge scan-write + edgenum (E) | node scan-write (N2)
__global__ void k_pass3(const int* __restrict__ ei, const int* __restrict__ rem,
                        const int* __restrict__ bsumsA, const int* __restrict__ bsumsB,
                        const int* __restrict__ totals,
                        const int* __restrict__ edge_num, const int* __restrict__ dropcnt,
                        const int* __restrict__ brmask,
                        int* __restrict__ edge_pos, int* __restrict__ remap,
                        float* __restrict__ out, long long base0,
                        int E, int N2, int G, int DE, int nbE){
  __shared__ int s[256];
  int b = blockIdx.x, t = threadIdx.x;
  if (b < nbE){
    int e = b*256 + t;
    int keep = 0, src = 0, dst = 0;
    if (e < E){ src = ei[e]; dst = ei[E + e]; keep = (rem[src] != e) ? 1 : 0; }
    int excl = excl_scan256(keep, s);
    long long ek = totals[0];
    if (e < E){
      if (keep){
        int p = bsumsA[b] + excl;
        edge_pos[e] = p;
        out[base0 + p]      = (float)src;
        out[base0 + ek + p] = (float)dst;
      } else edge_pos[e] = -1;
    }
    if (b == 0){
      long long off3 = base0 + 2*ek + ek*(long long)DE;
      for (int g = t; g < G; g += 256)
        out[off3 + g] = (float)(edge_num[g] - dropcnt[g]);
    }
  } else {
    int j = (b - nbE)*256 + t;
    int keep = (j < N2) ? (brmask[j] == 0) : 0;
    int excl = excl_scan256(keep, s);
    if (j < N2) remap[j] = keep ? (bsumsB[b - nbE] + excl) : -1;
  }
}

// ---------------- pass4: bredge blocksums (EB) | inform row copy (E rows) ---
// inform copy: 8 rows per 256-thread block, one 512B row per 32-lane group
// via float4 (16B/lane). Consecutive rows are contiguous in src and (when
// both kept) in dst -> full-wave 1KB coalesced transactions.
__global__ void __launch_bounds__(256) k_pass4(
    const int* __restrict__ bi, const int* __restrict__ remap,
    const float* __restrict__ inform, const int* __restrict__ edge_pos,
    const int* __restrict__ totals,
    int* __restrict__ bsumsC, float* __restrict__ out,
    long long base0, int EB, int E, int DE, int nbB){
  int b = blockIdx.x, t = threadIdx.x;
  if (b < nbB){
    __shared__ int s[256];
    int e = b*256 + t;
    int v = 0;
    if (e < EB) v = (remap[bi[e]] >= 0 && remap[bi[EB + e]] >= 0) ? 1 : 0;
    s[t] = v; __syncthreads();
    for (int off = 128; off > 0; off >>= 1){
      if (t < off) s[t] += s[t + off];
      __syncthreads();
    }
    if (t == 0) bsumsC[b] = s[0];
  } else {
    // 8 edge rows per block, 32 lanes x float4 per row
    int e = (b - nbB)*8 + (t >> 5);
    if (e >= E) return;
    int p = edge_pos[e];
    if (p < 0) return;
    long long ek   = totals[0];
    long long off2 = base0 + 2*ek;
    int lane = t & 31;
    const float4* in4 = (const float4*)(inform + (size_t)e * DE);
    float4*       o4  = (float4*)(out + off2 + (long long)p * DE);
    for (int j = lane; j < (DE >> 2); j += 32) o4[j] = in4[j];
  }
}

// ---------------- pass5: bredge scan-write (EB) | br_feature/br_batch (N2) --
// feature copy: 2 rows per 256-thread block, 128 lanes x float4 covers a
// 2KB (C=512) row in one iteration.
__global__ void __launch_bounds__(256) k_pass5(
    const int* __restrict__ bi, const int* __restrict__ remap,
    const int* __restrict__ bsumsC, const int* __restrict__ totals,
    const float* __restrict__ brf, const int* __restrict__ brb,
    float* __restrict__ out, long long base0,
    int G, int DE, int C, int EB, int N2, int nbB){
  int b = blockIdx.x, t = threadIdx.x;
  long long ek = totals[0], nk = totals[1], kc = totals[2];
  long long off4 = base0 + 2*ek + ek*(long long)DE + G;        // br_feature_p
  if (b < nbB){
    __shared__ int s[256];
    int e = b*256 + t;
    int r = -1, c = -1, keep = 0;
    if (e < EB){
      r = remap[bi[e]];
      c = remap[bi[EB + e]];
      keep = (r >= 0 && c >= 0) ? 1 : 0;
    }
    int excl = excl_scan256(keep, s);
    if (keep){
      long long off5 = off4 + nk*(long long)C;                 // br_index_p
      int p = bsumsC[b] + excl;
      out[off5 + p]      = (float)r;
      out[off5 + kc + p] = (float)c;
    }
  } else {
    int j = (b - nbB)*2 + (t >> 7);                            // node row
    if (j >= N2) return;
    int p = remap[j];
    if (p < 0) return;
    int lane = t & 127;
    const float4* in4 = (const float4*)(brf + (size_t)j * C);
    float4*       o4  = (float4*)(out + off4 + (long long)p * C);
    for (int k = lane; k < (C >> 2); k += 128) o4[k] = in4[k];
    if (lane == 0){
      long long off6 = off4 + nk*(long long)C + 2*kc;          // br_batch_p
      out[off6 + p] = (float)brb[j];
    }
  }
}

// ============================================================================
extern "C" void kernel_launch(void* const* d_in, const int* in_sizes, int n_in,
                              void* d_out, int out_size, void* d_ws, size_t ws_size,
                              hipStream_t stream){
  const float* x           = (const float*)d_in[0];
  const int*   edge_index  = (const int*)  d_in[1];
  const int*   edge_num    = (const int*)  d_in[2];
  const float* edge_inform = (const float*)d_in[3];
  const int*   batch       = (const int*)  d_in[4];
  const float* br_feature  = (const float*)d_in[5];
  const int*   br_index    = (const int*)  d_in[6];
  const int*   br_batch    = (const int*)  d_in[7];
  const int*   br_com_num  = (const int*)  d_in[8];
  const float* W           = (const float*)d_in[9];
  float* out = (float*)d_out;

  const int C  = in_sizes[9];          // W is (1, C)
  const int N  = in_sizes[4];          // batch
  const int G  = in_sizes[2];          // edge_num
  const int E  = in_sizes[1] / 2;      // edge_index (2, E)
  const int DE = in_sizes[3] / E;      // edge_inform (E, DE)
  const int N2 = in_sizes[7];          // br_batch
  const int EB = in_sizes[6] / 2;      // br_index (2, EB)

  // ---- workspace layout (ints); [counts..brmask] is the zeroed region ----
  int* ws        = (int*)d_ws;
  int* counts    = ws;                 // G   (zeroed)
  int* counts2   = counts    + G;      // G   (zeroed)
  int* dropcnt   = counts2   + G;      // G   (zeroed)
  int* brmask    = dropcnt   + G;      // N2  (zeroed; 0=keep, 1=dropped)
  int* node_off  = brmask    + N2;     // G
  int* node_off2 = node_off  + G;      // G
  int* e_off     = node_off2 + G;      // G
  int* totals    = e_off     + G;      // 8: [0]=e_kept [1]=n_kept [2]=kc
  int* low       = totals    + 8;      // N
  int* rem       = low       + N;      // N
  int* remap     = rem       + N;      // N2
  int* edge_pos  = remap     + N2;     // E
  int* bsumsA    = edge_pos  + E;      // 1024
  int* bsumsB    = bsumsA    + 1024;   // 1024
  int* bsumsC    = bsumsB    + 1024;   // 1024

  const long long base0 = (long long)N * C;   // end of x_out chunk

  const int nbN2 = (N2 + 255) / 256;
  const int nbE  = (E  + 255) / 256;   // <= 1024
  const int nbB  = (EB + 255) / 256;   // <= 1024

  hipMemsetAsync(counts, 0, sizeof(int) * (3 * (size_t)G + N2), stream);

  k_count_both<<<(N + N2 + 255) / 256, 256, 0, stream>>>(batch, N, br_batch, N2,
                                                         counts, counts2);
  k_scanG<<<1, 512, 0, stream>>>(counts, counts2, edge_num, G,
                                 node_off, node_off2, e_off);

  k_score<<<(N * 64 + 255) / 256, 256, 0, stream>>>(x, W, batch, counts, node_off,
                                                    out, low, rem, C, N);

  k_pass1<<<(max(E, N) + 255) / 256, 256, 0, stream>>>(
      edge_index, e_off, node_off, node_off2, counts, batch, low, br_com_num,
      rem, brmask, E, N, G);

  k_pass2<<<nbE + nbN2, 256, 0, stream>>>(edge_index, rem, e_off, brmask,
                                          dropcnt, bsumsA, bsumsB,
                                          E, N2, G, nbE);

  k_scanAB<<<2, 1024, 0, stream>>>(bsumsA, nbE, bsumsB, nbN2, totals);

  k_pass3<<<nbE + nbN2, 256, 0, stream>>>(edge_index, rem, bsumsA, bsumsB, totals,
                                          edge_num, dropcnt, brmask,
                                          edge_pos, remap, out, base0,
                                          E, N2, G, DE, nbE);

  k_pass4<<<nbB + (E + 7) / 8, 256, 0, stream>>>(br_index, remap,
                                                 edge_inform, edge_pos, totals,
                                                 bsumsC, out, base0,
                                                 EB, E, DE, nbB);

  k_scanC<<<1, 1024, 0, stream>>>(bsumsC, nbB, totals);

  k_pass5<<<nbB + (N2 + 1) / 2, 256, 0, stream>>>(br_index, remap, bsumsC, totals,
                                                  br_feature, br_batch, out, base0,
                                                  G, DE, C, EB, N2, nbB);
}